// Round 3
// baseline (101492.212 us; speedup 1.0000x reference)
//
#include <hip/hip_runtime.h>
#include <math.h>

#define TB 256      // batch
#define TT 512      // timesteps
#define TIN 128     // input size
#define TH 1024     // hidden
#define TOUT 9      // output coords
#define KD 1152     // TIN + TH

// ---- workspace layout (float offsets) ----
#define OFF_WG   0ull
#define SZ_WG    (256ull*1152ull*16ull)       // per-block gate weights [w][k][16]
#define OFF_WO2  (OFF_WG + SZ_WG)             // out-col weights [16][1152] (w<9 used)
#define SZ_WO2   (16ull*1152ull)
#define OFF_AP   (OFF_WO2 + SZ_WO2)           // A' = W_hh + Wo@W_h2o  [4096][1024]
#define SZ_AP    (4096ull*1024ull)
#define OFF_WCB  (OFF_AP + SZ_AP)             // W_combo [9][1024]
#define SZ_WCB   (9ull*1024ull)
#define OFF_BCB  (OFF_WCB + SZ_WCB)           // b_combo [9] (pad 16)
#define SZ_BCB   16ull
#define OFF_B0   (OFF_BCB + SZ_BCB)           // bias t==0 [4096]
#define OFF_BC   (OFF_B0 + 4096ull)           // bias t>0  [4096]
#define OFF_H0   (OFF_BC + 4096ull)           // h_cell ping [256][1024]
#define OFF_H1   (OFF_H0 + 262144ull)         // h_cell pong
#define OFF_GC   (OFF_H1 + 262144ull)         // [0]=barrier counter, [1]=abort flag
#define OFF_END  (OFF_GC + 16ull)             // ~37.9 MB total

// ---------------- prep kernels ----------------

// W_combo[r][m] = sum_j W_h2o[r][j]*W_h2h[j][m]; b_combo[r] = W_h2o[r]·b_h2h + b_h2o[r]
__global__ __launch_bounds__(256) void k_combo(const float* __restrict__ W_h2o,
                                               const float* __restrict__ W_h2h,
                                               const float* __restrict__ b_h2h,
                                               const float* __restrict__ b_h2o,
                                               float* __restrict__ Wcombo,
                                               float* __restrict__ bcombo) {
  int gid = blockIdx.x * 256 + threadIdx.x;
  if (gid < 9 * 1024) {
    int r = gid >> 10, m = gid & 1023;
    float s = 0.f;
    for (int j = 0; j < 1024; ++j) s += W_h2o[r * 1024 + j] * W_h2h[j * 1024 + m];
    Wcombo[gid] = s;
  }
  if (gid < 9) {
    float s = b_h2o[gid];
    for (int j = 0; j < 1024; ++j) s += W_h2o[gid * 1024 + j] * b_h2h[j];
    bcombo[gid] = s;
  }
}

// A'[col][j] = W_hh[col][j] + sum_r W_ih[col][128+r]*W_h2o[r][j]
__global__ __launch_bounds__(256) void k_aprime(const float* __restrict__ W_hh,
                                                const float* __restrict__ W_ih,
                                                const float* __restrict__ W_h2o,
                                                float* __restrict__ Ap) {
  int gid = blockIdx.x * 256 + threadIdx.x;
  int col = gid >> 10, j = gid & 1023;
  float s = W_hh[gid];
#pragma unroll
  for (int r = 0; r < 9; ++r) s += W_ih[col * 137 + 128 + r] * W_h2o[r * 1024 + j];
  Ap[gid] = s;
}

// Wh = A' @ W_h2h  -> scattered into Wg[w][128+m][c]
__global__ __launch_bounds__(256) void k_wh(const float* __restrict__ Ap,
                                            const float* __restrict__ W_h2h,
                                            float* __restrict__ Wg) {
  __shared__ float As2[16][68];
  __shared__ float Bs[16][68];
  const int tid = threadIdx.x;
  const int bm = (blockIdx.x & 15) * 64;   // m tile
  const int bc = (blockIdx.x >> 4) * 64;   // col tile
  const int tx = tid & 15, ty = tid >> 4;
  float acc[4][4];
#pragma unroll
  for (int i = 0; i < 4; ++i)
#pragma unroll
    for (int j = 0; j < 4; ++j) acc[i][j] = 0.f;

  for (int k0 = 0; k0 < 1024; k0 += 16) {
    {
      int cl = tid >> 2, kq = tid & 3;
      float4 v = *(const float4*)(Ap + (size_t)(bc + cl) * 1024 + k0 + kq * 4);
      As2[kq * 4 + 0][cl] = v.x; As2[kq * 4 + 1][cl] = v.y;
      As2[kq * 4 + 2][cl] = v.z; As2[kq * 4 + 3][cl] = v.w;
    }
    {
      int kk = tid >> 4, q = tid & 15;
      float4 v = *(const float4*)(W_h2h + (size_t)(k0 + kk) * 1024 + bm + q * 4);
      *(float4*)&Bs[kk][q * 4] = v;
    }
    __syncthreads();
#pragma unroll
    for (int kk = 0; kk < 16; ++kk) {
      float4 a = *(const float4*)&As2[kk][ty * 4];
      float4 bv = *(const float4*)&Bs[kk][tx * 4];
      acc[0][0] += a.x * bv.x; acc[0][1] += a.x * bv.y; acc[0][2] += a.x * bv.z; acc[0][3] += a.x * bv.w;
      acc[1][0] += a.y * bv.x; acc[1][1] += a.y * bv.y; acc[1][2] += a.y * bv.z; acc[1][3] += a.y * bv.w;
      acc[2][0] += a.z * bv.x; acc[2][1] += a.z * bv.y; acc[2][2] += a.z * bv.z; acc[2][3] += a.z * bv.w;
      acc[3][0] += a.w * bv.x; acc[3][1] += a.w * bv.y; acc[3][2] += a.w * bv.z; acc[3][3] += a.w * bv.w;
    }
    __syncthreads();
  }
#pragma unroll
  for (int i = 0; i < 4; ++i) {
#pragma unroll
    for (int j = 0; j < 4; ++j) {
      int col = bc + ty * 4 + i;          // global gate col 0..4095
      int m = bm + tx * 4 + j;            // h index 0..1023
      int q = col >> 10, colh = col & 1023;
      int w = colh >> 2, c = (q << 2) | (colh & 3);
      Wg[((size_t)w * KD + 128 + m) * 16 + c] = acc[i][j];
    }
  }
}

// biases: b0 = b_ih+b_hh ; bconst = b0 + W_hh·b_h2h + Wo·b_combo
__global__ __launch_bounds__(256) void k_bias(const float* __restrict__ b_ih,
                                              const float* __restrict__ b_hh,
                                              const float* __restrict__ W_hh,
                                              const float* __restrict__ W_ih,
                                              const float* __restrict__ b_h2h,
                                              const float* __restrict__ bcombo,
                                              float* __restrict__ b0,
                                              float* __restrict__ bconst) {
  int col = blockIdx.x * 256 + threadIdx.x;
  float base = b_ih[col] + b_hh[col];
  b0[col] = base;
  float s = 0.f;
  for (int j = 0; j < 1024; ++j) s += W_hh[(size_t)col * 1024 + j] * b_h2h[j];
#pragma unroll
  for (int r = 0; r < 9; ++r) s += W_ih[col * 137 + 128 + r] * bcombo[r];
  bconst[col] = base + s;
}

// x-part of Wg (k<128) and Wo2
__global__ __launch_bounds__(256) void k_fillx(const float* __restrict__ W_ih,
                                               const float* __restrict__ Wcombo,
                                               float* __restrict__ Wg,
                                               float* __restrict__ Wo2) {
  int gid = blockIdx.x * 256 + threadIdx.x;
  if (gid < 4096 * 128) {
    int col = gid >> 7, k = gid & 127;
    int q = col >> 10, colh = col & 1023;
    int w = colh >> 2, c = (q << 2) | (colh & 3);
    Wg[((size_t)w * KD + k) * 16 + c] = W_ih[col * 137 + k];
  }
  int g2 = gid - 4096 * 128;
  if (g2 >= 0 && g2 < 16 * KD) {
    int w = g2 / KD, k = g2 % KD;
    Wo2[g2] = (w < TOUT && k >= 128) ? Wcombo[w * 1024 + (k - 128)] : 0.f;
  }
}

// lengths passthrough (output 1)
__global__ void k_len(const int* __restrict__ len, float* __restrict__ dout) {
  int i = threadIdx.x;
  if (i < TB) dout[(size_t)TB * TT * TOUT + i] = (float)len[i];
}

// ---------------- main recurrent kernel ----------------
// 256 blocks (1/CU) x 512 threads. Block w owns gate cols {q*1024+4w..+3, q=0..3}
// (locally c=(q<<2)|jj) plus out col w (w<9). kq=tid>>7 (4-way K split), lane
// handles batches b=tid&127 and b+128. Weight addresses are wave-uniform.

__device__ __forceinline__ void seg(const float* __restrict__ wg,
                                    const float* __restrict__ wo,
                                    int kglob, int nk4,
                                    const float* __restrict__ a0r,
                                    const float* __restrict__ a1r,
                                    float4 (&s0)[4], float4 (&s1)[4],
                                    float& o0, float& o1) {
  const float4* wr = (const float4*)(wg + (size_t)kglob * 16);
  const float4* wv4 = (const float4*)(wo + kglob);
  const float4* A0 = (const float4*)a0r;
  const float4* A1 = (const float4*)a1r;
  for (int k4 = 0; k4 < nk4; ++k4) {
    float4 a0 = A0[k4], a1 = A1[k4];
    float4 ov = wv4[k4];
    o0 += a0.x * ov.x + a0.y * ov.y + a0.z * ov.z + a0.w * ov.w;
    o1 += a1.x * ov.x + a1.y * ov.y + a1.z * ov.z + a1.w * ov.w;
#pragma unroll
    for (int j = 0; j < 4; ++j) {
      const float ae0 = (j == 0) ? a0.x : (j == 1) ? a0.y : (j == 2) ? a0.z : a0.w;
      const float ae1 = (j == 0) ? a1.x : (j == 1) ? a1.y : (j == 2) ? a1.z : a1.w;
      const float4 w0 = wr[(size_t)k4 * 16 + j * 4 + 0];
      const float4 w1 = wr[(size_t)k4 * 16 + j * 4 + 1];
      const float4 w2 = wr[(size_t)k4 * 16 + j * 4 + 2];
      const float4 w3 = wr[(size_t)k4 * 16 + j * 4 + 3];
      s0[0].x += ae0 * w0.x; s0[0].y += ae0 * w0.y; s0[0].z += ae0 * w0.z; s0[0].w += ae0 * w0.w;
      s0[1].x += ae0 * w1.x; s0[1].y += ae0 * w1.y; s0[1].z += ae0 * w1.z; s0[1].w += ae0 * w1.w;
      s0[2].x += ae0 * w2.x; s0[2].y += ae0 * w2.y; s0[2].z += ae0 * w2.z; s0[2].w += ae0 * w2.w;
      s0[3].x += ae0 * w3.x; s0[3].y += ae0 * w3.y; s0[3].z += ae0 * w3.z; s0[3].w += ae0 * w3.w;
      s1[0].x += ae1 * w0.x; s1[0].y += ae1 * w0.y; s1[0].z += ae1 * w0.z; s1[0].w += ae1 * w0.w;
      s1[1].x += ae1 * w1.x; s1[1].y += ae1 * w1.y; s1[1].z += ae1 * w1.z; s1[1].w += ae1 * w1.w;
      s1[2].x += ae1 * w2.x; s1[2].y += ae1 * w2.y; s1[2].z += ae1 * w2.z; s1[2].w += ae1 * w2.w;
      s1[3].x += ae1 * w3.x; s1[3].y += ae1 * w3.y; s1[3].z += ae1 * w3.z; s1[3].w += ae1 * w3.w;
    }
  }
}

__device__ __forceinline__ float sigm(float v) { return 1.f / (1.f + __expf(-v)); }
__device__ __forceinline__ float tanh_f(float v) {
  float e2 = __expf(2.f * v);
  return (e2 - 1.f) / (e2 + 1.f);
}

__global__ __launch_bounds__(512, 1) void k_main(const float* __restrict__ x,
                                                 const float* __restrict__ Wg,
                                                 const float* __restrict__ Wo2,
                                                 const float* __restrict__ b0,
                                                 const float* __restrict__ bconst,
                                                 const float* __restrict__ bcombo,
                                                 float* __restrict__ h0buf,
                                                 float* __restrict__ h1buf,
                                                 unsigned* __restrict__ gcnt,
                                                 float* __restrict__ dout) {
  __shared__ float red[3][256][17];
  __shared__ float bias[2][17];
  __shared__ int sAbort;

  const int w = blockIdx.x;
  const int tid = threadIdx.x;
  const int kq = tid >> 7;
  const int b = tid & 127;
  const int b1 = b + 128;

  const float* wg = Wg + (size_t)w * (KD * 16);
  const float* wo = Wo2 + (size_t)w * KD;

  if (tid == 0) sAbort = 0;
  if (tid < 17) {
    int c = tid;
    int g = (c >> 2) * 1024 + (w << 2) + (c & 3);
    bias[0][c] = (c < 16) ? b0[g] : 0.f;
    bias[1][c] = (c < 16) ? bconst[g] : ((w < TOUT) ? bcombo[w] : 0.f);
  }
  float cs0[4] = {0.f, 0.f, 0.f, 0.f};
  float cs1[4] = {0.f, 0.f, 0.f, 0.f};
  __syncthreads();

  const float* ha = h0buf;   // h_cell(t-1), zeroed by memset
  float* hn = h1buf;

  for (int t = 0; t < TT; ++t) {
    float4 s0[4], s1[4];
#pragma unroll
    for (int r = 0; r < 4; ++r) {
      s0[r] = make_float4(0.f, 0.f, 0.f, 0.f);
      s1[r] = make_float4(0.f, 0.f, 0.f, 0.f);
    }
    float o0 = 0.f, o1 = 0.f;

    const float* h0r = ha + (size_t)b * TH;
    const float* h1r = ha + (size_t)b1 * TH;

    if (kq == 0) {
      seg(wg, wo, 0, 32, x + ((size_t)b * TT + t) * TIN, x + ((size_t)b1 * TT + t) * TIN, s0, s1, o0, o1);
      seg(wg, wo, 128, 40, h0r, h1r, s0, s1, o0, o1);
    } else {
      int kg = kq * 288;   // 288, 576, 864
      seg(wg, wo, kg, 72, h0r + (kg - 128), h1r + (kg - 128), s0, s1, o0, o1);
    }

    if (kq > 0) {
      float* r0 = &red[kq - 1][b][0];
      float* r1 = &red[kq - 1][b1][0];
#pragma unroll
      for (int r = 0; r < 4; ++r) {
        r0[r * 4 + 0] = s0[r].x; r0[r * 4 + 1] = s0[r].y; r0[r * 4 + 2] = s0[r].z; r0[r * 4 + 3] = s0[r].w;
        r1[r * 4 + 0] = s1[r].x; r1[r * 4 + 1] = s1[r].y; r1[r * 4 + 2] = s1[r].z; r1[r * 4 + 3] = s1[r].w;
      }
      r0[16] = o0; r1[16] = o1;
    }
    __syncthreads();

    if (kq == 0) {
      const float* bs = bias[(t > 0) ? 1 : 0];
      // ---- batch b ----
      {
        float v[17];
#pragma unroll
        for (int r = 0; r < 4; ++r) {
          v[r * 4 + 0] = s0[r].x; v[r * 4 + 1] = s0[r].y; v[r * 4 + 2] = s0[r].z; v[r * 4 + 3] = s0[r].w;
        }
        v[16] = o0;
#pragma unroll
        for (int c = 0; c < 17; ++c) v[c] += red[0][b][c] + red[1][b][c] + red[2][b][c] + bs[c];
        float4 hv;
#pragma unroll
        for (int jj = 0; jj < 4; ++jj) {
          float ig = sigm(v[jj]);
          float fg = sigm(v[4 + jj]);
          float gg = tanh_f(v[8 + jj]);
          float og = sigm(v[12 + jj]);
          float cn = fg * cs0[jj] + ig * gg;
          cs0[jj] = cn;
          ((float*)&hv)[jj] = og * tanh_f(cn);
        }
        *(float4*)(hn + (size_t)b * TH + (w << 2)) = hv;
        if (w < TOUT && t > 0) dout[((size_t)b * TT + (t - 1)) * TOUT + w] = v[16];
      }
      // ---- batch b1 ----
      {
        float v[17];
#pragma unroll
        for (int r = 0; r < 4; ++r) {
          v[r * 4 + 0] = s1[r].x; v[r * 4 + 1] = s1[r].y; v[r * 4 + 2] = s1[r].z; v[r * 4 + 3] = s1[r].w;
        }
        v[16] = o1;
#pragma unroll
        for (int c = 0; c < 17; ++c) v[c] += red[0][b1][c] + red[1][b1][c] + red[2][b1][c] + bs[c];
        float4 hv;
#pragma unroll
        for (int jj = 0; jj < 4; ++jj) {
          float ig = sigm(v[jj]);
          float fg = sigm(v[4 + jj]);
          float gg = tanh_f(v[8 + jj]);
          float og = sigm(v[12 + jj]);
          float cn = fg * cs1[jj] + ig * gg;
          cs1[jj] = cn;
          ((float*)&hv)[jj] = og * tanh_f(cn);
        }
        *(float4*)(hn + (size_t)b1 * TH + (w << 2)) = hv;
        if (w < TOUT && t > 0) dout[((size_t)b1 * TT + (t - 1)) * TOUT + w] = v[16];
      }
    }

    // ---- hang-proof grid barrier with global abort ----
    __syncthreads();
    __threadfence();
    if (tid == 0) {
      __hip_atomic_fetch_add(&gcnt[0], 1u, __ATOMIC_ACQ_REL, __HIP_MEMORY_SCOPE_AGENT);
      const unsigned tgt = (unsigned)(t + 1) * 256u;
      int guard = 0;
      while (__hip_atomic_load(&gcnt[0], __ATOMIC_RELAXED, __HIP_MEMORY_SCOPE_AGENT) < tgt) {
        __builtin_amdgcn_s_sleep(2);
        if (__hip_atomic_load(&gcnt[1], __ATOMIC_RELAXED, __HIP_MEMORY_SCOPE_AGENT) != 0u) {
          sAbort = 1; break;                       // someone else timed out -> bail
        }
        if (++guard > 65536) {                     // ~10-20 ms cap
          __hip_atomic_store(&gcnt[1], 1u, __ATOMIC_RELEASE, __HIP_MEMORY_SCOPE_AGENT);
          sAbort = 1; break;                       // release the whole grid
        }
      }
    }
    __syncthreads();
    if (sAbort) return;   // whole block exits; other blocks see gcnt[1] and exit too
    __threadfence();

    const float* tp = ha; ha = hn; hn = (float*)tp;
  }

  // ---- epilogue: out(T-1) = h_cell(T-1)·W_combo[w] + b_combo[w] ----
  if (kq == 0 && w < TOUT) {
    const float4* wv4 = (const float4*)(wo + 128);
#pragma unroll
    for (int pb = 0; pb < 2; ++pb) {
      int bb = b + pb * 128;
      const float4* hr = (const float4*)(ha + (size_t)bb * TH);
      float s = 0.f;
      for (int k4 = 0; k4 < 256; ++k4) {
        float4 a = hr[k4]; float4 wv = wv4[k4];
        s += a.x * wv.x + a.y * wv.y + a.z * wv.z + a.w * wv.w;
      }
      dout[((size_t)bb * TT + (TT - 1)) * TOUT + w] = s + bias[1][16];
    }
  }
}

// ---------------- launch ----------------

extern "C" void kernel_launch(void* const* d_in, const int* in_sizes, int n_in,
                              void* d_out, int out_size, void* d_ws, size_t ws_size,
                              hipStream_t stream) {
  if (ws_size < (size_t)OFF_END * sizeof(float)) return;   // workspace too small: clean fail

  const float* x     = (const float*)d_in[0];
  const float* W_ih  = (const float*)d_in[1];
  const float* b_ih  = (const float*)d_in[2];
  const float* W_hh  = (const float*)d_in[3];
  const float* b_hh  = (const float*)d_in[4];
  const float* W_h2h = (const float*)d_in[5];
  const float* b_h2h = (const float*)d_in[6];
  const float* W_h2o = (const float*)d_in[7];
  const float* b_h2o = (const float*)d_in[8];
  const int*   lens  = (const int*)d_in[9];

  float* wsf    = (float*)d_ws;
  float* dout   = (float*)d_out;
  float* Wg     = wsf + OFF_WG;
  float* Wo2    = wsf + OFF_WO2;
  float* Ap     = wsf + OFF_AP;
  float* Wcombo = wsf + OFF_WCB;
  float* bcombo = wsf + OFF_BCB;
  float* b0     = wsf + OFF_B0;
  float* bconst = wsf + OFF_BC;
  float* h0     = wsf + OFF_H0;
  float* h1     = wsf + OFF_H1;
  unsigned* gcnt = (unsigned*)(wsf + OFF_GC);

  // zero h ping-pong + barrier counter + abort flag every call (graph-replay safe)
  hipMemsetAsync((void*)(wsf + OFF_H0), 0, (size_t)(OFF_END - OFF_H0) * sizeof(float), stream);

  k_combo<<<36, 256, 0, stream>>>(W_h2o, W_h2h, b_h2h, b_h2o, Wcombo, bcombo);
  k_aprime<<<16384, 256, 0, stream>>>(W_hh, W_ih, W_h2o, Ap);
  k_wh<<<1024, 256, 0, stream>>>(Ap, W_h2h, Wg);
  k_bias<<<16, 256, 0, stream>>>(b_ih, b_hh, W_hh, W_ih, b_h2h, bcombo, b0, bconst);
  k_fillx<<<2121, 256, 0, stream>>>(W_ih, Wcombo, Wg, Wo2);
  k_len<<<1, 256, 0, stream>>>(lens, dout);

  k_main<<<256, 512, 0, stream>>>(x, Wg, Wo2, b0, bconst, bcombo, h0, h1, gcnt, dout);
}